// Round 6
// baseline (441.542 us; speedup 1.0000x reference)
//
#include <hip/hip_runtime.h>
#include <hip/hip_bf16.h>

typedef unsigned short u16;
typedef unsigned int u32;
typedef __attribute__((ext_vector_type(8))) short short8;
typedef __attribute__((ext_vector_type(4))) float f32x4;

// aliasing-safe types for type-punned global/LDS access
typedef float __attribute__((may_alias)) f32a;
typedef __attribute__((ext_vector_type(2))) float f32x2_t;
typedef f32x2_t __attribute__((may_alias)) f32x2a;
typedef __attribute__((ext_vector_type(4))) float f32x4_t;
typedef f32x4_t __attribute__((may_alias)) f32x4a;
typedef __attribute__((ext_vector_type(2))) u32 u32x2_t;
typedef u32x2_t __attribute__((may_alias)) u32x2a;

#define NSLOPE 0.2f
#define BNEPS  1e-5f

union U8 { short8 s; u16 u[8]; u32 w[4]; };

__device__ __forceinline__ u16 f2bf_scalar(float f) {
    union { float f; u32 i; } x; x.f = f;
    u32 u = x.i + 0x7FFFu + ((x.i >> 16) & 1u);
    return (u16)(u >> 16);
}

// packed f32x2 -> bf16x2 (RNE). gfx950 has v_cvt_pk_bf16_f32.
__device__ __forceinline__ u32 cvt2(float a, float b) {
#if __has_builtin(__builtin_amdgcn_cvt_pk_bf16_f32)
    auto p = __builtin_amdgcn_cvt_pk_bf16_f32(a, b);
    u32 w; __builtin_memcpy(&w, &p, sizeof(u32));
    return w;
#else
    return (u32)f2bf_scalar(a) | ((u32)f2bf_scalar(b) << 16);
#endif
}
__device__ __forceinline__ u16 cvt1(float a) { return (u16)cvt2(a, a); }

// lrelu = max(x, 0.2x): 2 VALU ops, exact for all x
__device__ __forceinline__ float lrelu(float x) { return fmaxf(x, NSLOPE * x); }

// B-fragment for mfma_f32_16x16x32_bf16 from fp32 global W:
// lane holds B[k = ks*32 + q*8 + j][n = nt*16 + t]
__device__ __forceinline__ short8 load_bfrag(const void* W, int K, int Cn, int ks, int nt,
                                             int q, int t) {
    U8 x;
#pragma unroll
    for (int j = 0; j < 8; ++j) {
        int k = ks * 32 + q * 8 + j;
        x.u[j] = (k < K) ? f2bf_scalar(((const f32a*)W)[(size_t)k * Cn + nt * 16 + t]) : (u16)0;
    }
    return x.s;
}

// A-fragment from per-wave LDS tile row-major [16][68] bf16 — two b64 reads
// (row*136 + ks*64 + q*16 bytes: 8B-aligned). Same-wave DS is in-order.
__device__ __forceinline__ short8 lds_afrag(const u16* buf, int row, int ks, int q) {
    const u16* cp = buf + row * 68 + ks * 32 + q * 8;
    u32x2a a = *(const u32x2a*)cp;
    u32x2a b = *(const u32x2a*)(cp + 4);
    U8 x; x.w[0] = a.x; x.w[1] = a.y; x.w[2] = b.x; x.w[3] = b.y;
    return x.s;
}

__device__ __forceinline__ float ldf(const void* p, size_t i) { return ((const f32a*)p)[i]; }

#define MFMA(a, b, c) __builtin_amdgcn_mfma_f32_16x16x32_bf16((a), (b), (c), 0, 0, 0)

struct G8 { float v[8]; };

// One wave = one group of 16 points. LDS tiles are PER-WAVE: no in-loop barriers.
__global__ __launch_bounds__(256, 4) void lfa_kernel(
    const void* __restrict__ feat,        // (131072, 32) fp32
    const void* __restrict__ rawf,        // (131072*16, 10) fp32
    const int*  __restrict__ nbidx,       // (131072, 16) int32
    const void* __restrict__ w_raw,
    const void* __restrict__ b_raw, const void* __restrict__ g_raw,
    const void* __restrict__ be_raw, const void* __restrict__ m_raw,
    const void* __restrict__ v_raw,
    const void* __restrict__ w_nb,
    const void* __restrict__ b_nb, const void* __restrict__ g_nb,
    const void* __restrict__ be_nb, const void* __restrict__ m_nb,
    const void* __restrict__ v_nb,
    const void* __restrict__ w_attn,
    const void* __restrict__ w_out,
    const void* __restrict__ b_out, const void* __restrict__ g_out,
    const void* __restrict__ be_out, const void* __restrict__ m_out,
    const void* __restrict__ v_out,
    const void* __restrict__ w_sc,
    const void* __restrict__ b_sc, const void* __restrict__ g_sc,
    const void* __restrict__ be_sc, const void* __restrict__ m_sc,
    const void* __restrict__ v_sc,
    float* __restrict__ outp)             // (131072, 64) fp32
{
    __shared__ __align__(16) u16 s_cat[4][16 * 68];
    __shared__ __align__(16) u16 s_h[4][16 * 68];
    __shared__ __align__(16) u16 s_pool[4][16 * 68];
    __shared__ float2 s_pr_raw[32];
    __shared__ float2 s_pr_nb[64];
    __shared__ float2 s_pr_out[64];
    __shared__ float2 s_pr_sc[64];

    const int tid  = threadIdx.x;
    const int lane = tid & 63;
    const int wv   = tid >> 6;
    const int t    = lane & 15;
    const int q    = lane >> 4;

    // ---- fold BN (+linear bias) into per-channel scale/bias ----
    if (tid < 64) {
        int c = tid;
        float s = ldf(g_nb, c) * rsqrtf(ldf(v_nb, c) + BNEPS);
        s_pr_nb[c] = make_float2(s, (ldf(b_nb, c) - ldf(m_nb, c)) * s + ldf(be_nb, c));
    } else if (tid < 128) {
        int c = tid - 64;
        float s = ldf(g_out, c) * rsqrtf(ldf(v_out, c) + BNEPS);
        s_pr_out[c] = make_float2(s, (ldf(b_out, c) - ldf(m_out, c)) * s + ldf(be_out, c));
    } else if (tid < 192) {
        int c = tid - 128;
        float s = ldf(g_sc, c) * rsqrtf(ldf(v_sc, c) + BNEPS);
        s_pr_sc[c] = make_float2(s, (ldf(b_sc, c) - ldf(m_sc, c)) * s + ldf(be_sc, c));
    } else if (tid < 224) {
        int c = tid - 192;
        float s = ldf(g_raw, c) * rsqrtf(ldf(v_raw, c) + BNEPS);
        s_pr_raw[c] = make_float2(s, (ldf(b_raw, c) - ldf(m_raw, c)) * s + ldf(be_raw, c));
    }
    __syncthreads();   // the ONLY block-wide barrier (BN tables shared by all waves)

    // ---- loop-phase weight B-fragments (w_out/w_sc reloaded in epilogue) ----
    short8 wraw[2], wnb[2][4], watt[2][4];
#pragma unroll
    for (int nt = 0; nt < 2; ++nt) wraw[nt] = load_bfrag(w_raw, 10, 32, 0, nt, q, t);
#pragma unroll
    for (int ks = 0; ks < 2; ++ks)
#pragma unroll
        for (int nt = 0; nt < 4; ++nt) {
            wnb[ks][nt]  = load_bfrag(w_nb,   64, 64, ks, nt, q, t);
            watt[ks][nt] = load_bfrag(w_attn, 64, 64, ks, nt, q, t);
        }

    u16* catw  = &s_cat[wv][0];
    u16* hw    = &s_h[wv][0];
    u16* poolw = &s_pool[wv][0];

    const f32x4 zf = {0.f, 0.f, 0.f, 0.f};
    const int g  = blockIdx.x * 4 + wv;     // 8192 groups, grid 2048 x 4 waves
    const int P0 = g * 16;
    const int bb = P0 >> 16;                // group never straddles batch boundary
    const size_t fb = (size_t)bb << 16;

    const int m_ = lane >> 2;               // gather: neighbor index this lane handles
    const int pc = lane & 3;                // gather: 8-float piece

    auto load_gather = [&](int ix) {
        const float* fp = (const float*)feat + (fb + (size_t)ix) * 32 + pc * 8;
        f32x4a a = *(const f32x4a*)fp;
        f32x4a b = *(const f32x4a*)(fp + 4);
        G8 r;
        r.v[0]=a.x; r.v[1]=a.y; r.v[2]=a.z; r.v[3]=a.w;
        r.v[4]=b.x; r.v[5]=b.y; r.v[6]=b.z; r.v[7]=b.w;
        return r;
    };
    auto load_raw = [&](int p) {
        G8 r;
#pragma unroll
        for (int j = 0; j < 8; ++j) r.v[j] = 0.f;
        const f32a* rp = (const f32a*)rawf + (size_t)(P0 + p) * 160 + (size_t)t * 10;
        if (q == 0) {           // 8B-aligned f32x2 loads (t*40 % 8 == 0)
            f32x2a a = *(const f32x2a*)rp;
            f32x2a b = *(const f32x2a*)(rp + 2);
            f32x2a c = *(const f32x2a*)(rp + 4);
            f32x2a d = *(const f32x2a*)(rp + 6);
            r.v[0]=a.x; r.v[1]=a.y; r.v[2]=b.x; r.v[3]=b.y;
            r.v[4]=c.x; r.v[5]=c.y; r.v[6]=d.x; r.v[7]=d.y;
        } else if (q == 1) {
            f32x2a a = *(const f32x2a*)(rp + 8);
            r.v[0]=a.x; r.v[1]=a.y;
        }
        return r;
    };

    // ---- software-pipeline preamble ----
    int ixA = nbidx[P0 * 16 + m_];
    int ixB = nbidx[(P0 + 1) * 16 + m_];
    G8 gA = load_gather(ixA);
    G8 rA = load_raw(0);

#pragma unroll 1
    for (int p = 0; p < 16; ++p) {
        // ---- issue next iteration's loads first (latency cover) ----
        G8 gB, rB; int ixC = ixB;
        if (p < 15) {
            gB = load_gather(ixB);
            rB = load_raw(p + 1);
            ixC = nbidx[(P0 + ((p + 2 < 16) ? p + 2 : 15)) * 16 + m_];
        } else {
            gB = gA; rB = rA;
        }

        // ---- phase A: gather -> cat[m][0..31] (packed cvt + b64 LDS writes) ----
        {
            u32x2a lo, hi;
            lo.x = cvt2(gA.v[0], gA.v[1]); lo.y = cvt2(gA.v[2], gA.v[3]);
            hi.x = cvt2(gA.v[4], gA.v[5]); hi.y = cvt2(gA.v[6], gA.v[7]);
            *(u32x2a*)(catw + m_ * 68 + pc * 8)     = lo;
            *(u32x2a*)(catw + m_ * 68 + pc * 8 + 4) = hi;
        }
        // ---- raw MLP via MFMA -> cat[m][32..63] ----
        {
            U8 au;
            au.w[0] = cvt2(rA.v[0], rA.v[1]); au.w[1] = cvt2(rA.v[2], rA.v[3]);
            au.w[2] = cvt2(rA.v[4], rA.v[5]); au.w[3] = cvt2(rA.v[6], rA.v[7]);
            short8 ar = au.s;
            f32x4 racc[2];
            racc[0] = MFMA(ar, wraw[0], zf);
            racc[1] = MFMA(ar, wraw[1], zf);
#pragma unroll
            for (int nt = 0; nt < 2; ++nt) {
                int c = nt * 16 + t;
                float2 pr = s_pr_raw[c];
#pragma unroll
                for (int r = 0; r < 4; ++r) {
                    float x = lrelu(fmaf(racc[nt][r], pr.x, pr.y));
                    catw[(q * 4 + r) * 68 + 32 + c] = cvt1(x);
                }
            }
        }

        // ---- phase B: h = lrelu(bn(cat @ w_nb)) ----
        short8 a0 = lds_afrag(catw, t, 0, q);
        short8 a1 = lds_afrag(catw, t, 1, q);
        float hv[4][4];
#pragma unroll
        for (int nt = 0; nt < 4; ++nt) {
            f32x4 a = zf;
            a = MFMA(a0, wnb[0][nt], a);
            a = MFMA(a1, wnb[1][nt], a);
            float2 pr = s_pr_nb[nt * 16 + t];
#pragma unroll
            for (int r = 0; r < 4; ++r) {
                hv[nt][r] = lrelu(fmaf(a[r], pr.x, pr.y));
                hw[(q * 4 + r) * 68 + nt * 16 + t] = cvt1(hv[nt][r]);
            }
        }

        // ---- phase C: scores = h @ w_attn; softmax over m (no max-sub: |s|<<88); pool ----
        short8 h0 = lds_afrag(hw, t, 0, q);
        short8 h1 = lds_afrag(hw, t, 1, q);
        float pooled[4];
#pragma unroll
        for (int nt = 0; nt < 4; ++nt) {
            f32x4 s = zf;
            s = MFMA(h0, watt[0][nt], s);
            s = MFMA(h1, watt[1][nt], s);
            float num = 0.f, den = 0.f;
#pragma unroll
            for (int r = 0; r < 4; ++r) {
                float e = __expf(s[r]);
                num += e * hv[nt][r];
                den += e;
            }
            num += __shfl_xor(num, 16); den += __shfl_xor(den, 16);
            num += __shfl_xor(num, 32); den += __shfl_xor(den, 32);
            pooled[nt] = num / den;
        }
        float pv = (q == 0) ? pooled[0] : (q == 1) ? pooled[1]
                 : (q == 2) ? pooled[2] : pooled[3];
        poolw[p * 68 + q * 16 + t] = cvt1(pv);

        // rotate pipeline buffers
        gA = gB; rA = rB; ixB = ixC;
    }

    // ---- epilogue: out = bn(pooled @ w_out); sc = bn(feat @ w_sc); lrelu(sum) ----
    short8 wout[2][4], wsc[4];
#pragma unroll
    for (int ks = 0; ks < 2; ++ks)
#pragma unroll
        for (int nt = 0; nt < 4; ++nt) wout[ks][nt] = load_bfrag(w_out, 64, 64, ks, nt, q, t);
#pragma unroll
    for (int nt = 0; nt < 4; ++nt) wsc[nt] = load_bfrag(w_sc, 32, 64, 0, nt, q, t);

    short8 pf0 = lds_afrag(poolw, t, 0, q);
    short8 pf1 = lds_afrag(poolw, t, 1, q);
    U8 sxu;
    {
        const float* fp = (const float*)feat + (size_t)(P0 + t) * 32 + q * 8;
        f32x4a v0 = *(const f32x4a*)fp;
        f32x4a v1 = *(const f32x4a*)(fp + 4);
        sxu.w[0] = cvt2(v0.x, v0.y); sxu.w[1] = cvt2(v0.z, v0.w);
        sxu.w[2] = cvt2(v1.x, v1.y); sxu.w[3] = cvt2(v1.z, v1.w);
    }
    short8 scf = sxu.s;
#pragma unroll
    for (int nt = 0; nt < 4; ++nt) {
        f32x4 oa = zf;
        oa = MFMA(pf0, wout[0][nt], oa);
        oa = MFMA(pf1, wout[1][nt], oa);
        f32x4 sa = MFMA(scf, wsc[nt], zf);
        float2 po = s_pr_out[nt * 16 + t];
        float2 ps = s_pr_sc[nt * 16 + t];
#pragma unroll
        for (int r = 0; r < 4; ++r) {
            float o  = fmaf(oa[r], po.x, po.y);
            float s2 = fmaf(sa[r], ps.x, ps.y);
            outp[(size_t)(P0 + q * 4 + r) * 64 + nt * 16 + t] = lrelu(o + s2);
        }
    }
}

extern "C" void kernel_launch(void* const* d_in, const int* in_sizes, int n_in,
                              void* d_out, int out_size, void* d_ws, size_t ws_size,
                              hipStream_t stream) {
    hipLaunchKernelGGL(lfa_kernel, dim3(2048), dim3(256), 0, stream,
                       d_in[0], d_in[1], (const int*)d_in[2],
                       d_in[3], d_in[4], d_in[5], d_in[6], d_in[7], d_in[8],
                       d_in[9], d_in[10], d_in[11], d_in[12], d_in[13], d_in[14],
                       d_in[15],
                       d_in[16], d_in[17], d_in[18], d_in[19], d_in[20], d_in[21],
                       d_in[22], d_in[23], d_in[24], d_in[25], d_in[26], d_in[27],
                       (float*)d_out);
}

// Round 7
// 295.499 us; speedup vs baseline: 1.4942x; 1.4942x over previous
//
#include <hip/hip_runtime.h>
#include <hip/hip_bf16.h>

typedef unsigned short u16;
typedef unsigned int u32;
typedef __attribute__((ext_vector_type(8))) short short8;
typedef __attribute__((ext_vector_type(4))) float f32x4;

// aliasing-safe types for type-punned global/LDS access
typedef float __attribute__((may_alias)) f32a;
typedef __attribute__((ext_vector_type(2))) float f32x2_t;
typedef f32x2_t __attribute__((may_alias)) f32x2a;
typedef __attribute__((ext_vector_type(4))) float f32x4_t;
typedef f32x4_t __attribute__((may_alias)) f32x4a;
typedef __attribute__((ext_vector_type(2))) u32 u32x2_t;
typedef u32x2_t __attribute__((may_alias)) u32x2a;

#define NSLOPE 0.2f
#define BNEPS  1e-5f

union U8 { short8 s; u16 u[8]; u32 w[4]; };

__device__ __forceinline__ u16 f2bf_scalar(float f) {
    union { float f; u32 i; } x; x.f = f;
    u32 u = x.i + 0x7FFFu + ((x.i >> 16) & 1u);
    return (u16)(u >> 16);
}

// packed f32x2 -> bf16x2 (RNE). gfx950 has v_cvt_pk_bf16_f32.
__device__ __forceinline__ u32 cvt2(float a, float b) {
#if __has_builtin(__builtin_amdgcn_cvt_pk_bf16_f32)
    auto p = __builtin_amdgcn_cvt_pk_bf16_f32(a, b);
    u32 w; __builtin_memcpy(&w, &p, sizeof(u32));
    return w;
#else
    return (u32)f2bf_scalar(a) | ((u32)f2bf_scalar(b) << 16);
#endif
}
__device__ __forceinline__ u16 cvt1(float a) { return (u16)cvt2(a, a); }

// lrelu = max(x, 0.2x): 2 VALU ops, exact for all x
__device__ __forceinline__ float lrelu(float x) { return fmaxf(x, NSLOPE * x); }

// B-fragment for mfma_f32_16x16x32_bf16 from fp32 global W:
// lane holds B[k = ks*32 + q*8 + j][n = nt*16 + t]
__device__ __forceinline__ short8 load_bfrag(const void* W, int K, int Cn, int ks, int nt,
                                             int q, int t) {
    U8 x;
#pragma unroll
    for (int j = 0; j < 8; ++j) {
        int k = ks * 32 + q * 8 + j;
        x.u[j] = (k < K) ? f2bf_scalar(((const f32a*)W)[(size_t)k * Cn + nt * 16 + t]) : (u16)0;
    }
    return x.s;
}

// A-fragment from per-wave LDS tile row-major [16][68] bf16 — two b64 reads
// (byte addr row*136 + ks*64 + q*16: 8B-aligned). Same-wave DS is in-order.
__device__ __forceinline__ short8 lds_afrag(const u16* buf, int row, int ks, int q) {
    const u16* cp = buf + row * 68 + ks * 32 + q * 8;
    u32x2a a = *(const u32x2a*)cp;
    u32x2a b = *(const u32x2a*)(cp + 4);
    U8 x; x.w[0] = a.x; x.w[1] = a.y; x.w[2] = b.x; x.w[3] = b.y;
    return x.s;
}

__device__ __forceinline__ float ldf(const void* p, size_t i) { return ((const f32a*)p)[i]; }

#define MFMA(a, b, c) __builtin_amdgcn_mfma_f32_16x16x32_bf16((a), (b), (c), 0, 0, 0)

// One wave = one group of 16 points. LDS tiles are PER-WAVE: no in-loop barriers.
// launch_bounds(256,3): VGPR cap 168 — R6's (256,4) spilled (FETCH 189->503 MB). Do not raise.
__global__ __launch_bounds__(256, 3) void lfa_kernel(
    const void* __restrict__ feat,        // (131072, 32) fp32
    const void* __restrict__ rawf,        // (131072*16, 10) fp32
    const int*  __restrict__ nbidx,       // (131072, 16) int32
    const void* __restrict__ w_raw,
    const void* __restrict__ b_raw, const void* __restrict__ g_raw,
    const void* __restrict__ be_raw, const void* __restrict__ m_raw,
    const void* __restrict__ v_raw,
    const void* __restrict__ w_nb,
    const void* __restrict__ b_nb, const void* __restrict__ g_nb,
    const void* __restrict__ be_nb, const void* __restrict__ m_nb,
    const void* __restrict__ v_nb,
    const void* __restrict__ w_attn,
    const void* __restrict__ w_out,
    const void* __restrict__ b_out, const void* __restrict__ g_out,
    const void* __restrict__ be_out, const void* __restrict__ m_out,
    const void* __restrict__ v_out,
    const void* __restrict__ w_sc,
    const void* __restrict__ b_sc, const void* __restrict__ g_sc,
    const void* __restrict__ be_sc, const void* __restrict__ m_sc,
    const void* __restrict__ v_sc,
    float* __restrict__ outp)             // (131072, 64) fp32
{
    __shared__ __align__(16) u16 s_cat[4][16 * 68];
    __shared__ __align__(16) u16 s_h[4][16 * 68];
    __shared__ __align__(16) u16 s_pool[4][16 * 68];
    __shared__ float2 s_pr_raw[32];
    __shared__ float2 s_pr_nb[64];
    __shared__ float2 s_pr_out[64];
    __shared__ float2 s_pr_sc[64];

    const int tid  = threadIdx.x;
    const int lane = tid & 63;
    const int wv   = tid >> 6;
    const int t    = lane & 15;
    const int q    = lane >> 4;

    // ---- fold BN (+linear bias) into per-channel scale/bias ----
    if (tid < 64) {
        int c = tid;
        float s = ldf(g_nb, c) * rsqrtf(ldf(v_nb, c) + BNEPS);
        s_pr_nb[c] = make_float2(s, (ldf(b_nb, c) - ldf(m_nb, c)) * s + ldf(be_nb, c));
    } else if (tid < 128) {
        int c = tid - 64;
        float s = ldf(g_out, c) * rsqrtf(ldf(v_out, c) + BNEPS);
        s_pr_out[c] = make_float2(s, (ldf(b_out, c) - ldf(m_out, c)) * s + ldf(be_out, c));
    } else if (tid < 192) {
        int c = tid - 128;
        float s = ldf(g_sc, c) * rsqrtf(ldf(v_sc, c) + BNEPS);
        s_pr_sc[c] = make_float2(s, (ldf(b_sc, c) - ldf(m_sc, c)) * s + ldf(be_sc, c));
    } else if (tid < 224) {
        int c = tid - 192;
        float s = ldf(g_raw, c) * rsqrtf(ldf(v_raw, c) + BNEPS);
        s_pr_raw[c] = make_float2(s, (ldf(b_raw, c) - ldf(m_raw, c)) * s + ldf(be_raw, c));
    }
    __syncthreads();   // the ONLY block-wide barrier (BN tables shared by all waves)

    // ---- loop-phase weight B-fragments (w_out/w_sc reloaded in epilogue) ----
    short8 wraw[2], wnb[2][4], watt[2][4];
#pragma unroll
    for (int nt = 0; nt < 2; ++nt) wraw[nt] = load_bfrag(w_raw, 10, 32, 0, nt, q, t);
#pragma unroll
    for (int ks = 0; ks < 2; ++ks)
#pragma unroll
        for (int nt = 0; nt < 4; ++nt) {
            wnb[ks][nt]  = load_bfrag(w_nb,   64, 64, ks, nt, q, t);
            watt[ks][nt] = load_bfrag(w_attn, 64, 64, ks, nt, q, t);
        }

    u16* catw  = &s_cat[wv][0];
    u16* hw    = &s_h[wv][0];
    u16* poolw = &s_pool[wv][0];

    const f32x4 zf = {0.f, 0.f, 0.f, 0.f};
    const int g  = blockIdx.x * 4 + wv;     // 8192 groups, grid 2048 x 4 waves
    const int P0 = g * 16;
    const int bb = P0 >> 16;                // group never straddles batch boundary
    const size_t fb = (size_t)bb << 16;

    const int m_ = lane >> 2;               // gather: neighbor index this lane handles
    const int pc = lane & 3;                // gather: 8-float piece

    // hoisted per-wave base pointers
    const int*  nbp  = nbidx + P0 * 16 + m_;                       // idx for point p: nbp[p*16]
    const f32a* rawp = (const f32a*)rawf + (size_t)P0 * 160 + (size_t)t * 10;  // + p*160
    const float* fpb = (const float*)feat;

    // branch-free loaders -> SSA f32x4 pairs (no structs: avoid private-stack demotion)
    auto load_gather = [&](int ix, f32x4& a, f32x4& b) {
        const float* fp = fpb + (fb + (size_t)ix) * 32 + pc * 8;
        a = *(const f32x4a*)fp;
        b = *(const f32x4a*)(fp + 4);
    };
    auto load_raw = [&](int p, f32x4& a, f32x4& b) {
        // lane(t,q) needs raw[t][k], k = q*8+j ; rows are 10 floats (only 8B-aligned)
        const f32a* rp = rawp + (size_t)p * 160;
        f32x2a r01 = *(const f32x2a*)rp;
        f32x2a r23 = *(const f32x2a*)(rp + 2);
        f32x2a r45 = *(const f32x2a*)(rp + 4);
        f32x2a r67 = *(const f32x2a*)(rp + 6);
        f32x2a r89 = *(const f32x2a*)(rp + 8);
        float q0 = (q == 0) ? 1.f : 0.f;
        float q1 = (q == 1) ? 1.f : 0.f;
        a.x = q0 * r01.x + q1 * r89.x;   // k=0 slot: q0 -> raw[0], q1 -> raw[8]
        a.y = q0 * r01.y + q1 * r89.y;   // k=1 slot: q0 -> raw[1], q1 -> raw[9]
        a.z = q0 * r23.x; a.w = q0 * r23.y;
        b.x = q0 * r45.x; b.y = q0 * r45.y;
        b.z = q0 * r67.x; b.w = q0 * r67.y;
    };

    // ---- software-pipeline preamble (depth 1 for data, 2 for indices) ----
    int ixA = nbp[0];
    int ixB = nbp[16];
    f32x4 ga0, ga1, ra0, ra1;
    load_gather(ixA, ga0, ga1);
    load_raw(0, ra0, ra1);

#pragma unroll 1
    for (int p = 0; p < 16; ++p) {
        // ---- issue next iteration's loads first (latency cover); clamped, branch-free ----
        const int pn  = (p + 1 < 16) ? p + 1 : 15;
        const int pnn = (p + 2 < 16) ? p + 2 : 15;
        f32x4 gb0, gb1, rb0, rb1;
        load_gather(ixB, gb0, gb1);
        load_raw(pn, rb0, rb1);
        int ixC = nbp[pnn * 16];

        // ---- phase A: gather -> cat[m][0..31] (packed cvt + b64 LDS writes) ----
        {
            u32x2a lo, hi;
            lo.x = cvt2(ga0.x, ga0.y); lo.y = cvt2(ga0.z, ga0.w);
            hi.x = cvt2(ga1.x, ga1.y); hi.y = cvt2(ga1.z, ga1.w);
            *(u32x2a*)(catw + m_ * 68 + pc * 8)     = lo;
            *(u32x2a*)(catw + m_ * 68 + pc * 8 + 4) = hi;
        }
        // ---- raw MLP via MFMA (K 10 padded to 32) -> cat[m][32..63] ----
        {
            U8 au;
            au.w[0] = cvt2(ra0.x, ra0.y); au.w[1] = cvt2(ra0.z, ra0.w);
            au.w[2] = cvt2(ra1.x, ra1.y); au.w[3] = cvt2(ra1.z, ra1.w);
            short8 ar = au.s;
            f32x4 racc[2];
            racc[0] = MFMA(ar, wraw[0], zf);
            racc[1] = MFMA(ar, wraw[1], zf);
#pragma unroll
            for (int nt = 0; nt < 2; ++nt) {
                int c = nt * 16 + t;
                float2 pr = s_pr_raw[c];
#pragma unroll
                for (int r = 0; r < 4; ++r) {
                    float x = lrelu(fmaf(racc[nt][r], pr.x, pr.y));
                    catw[(q * 4 + r) * 68 + 32 + c] = cvt1(x);
                }
            }
        }

        // ---- phase B: h = lrelu(bn(cat @ w_nb)) ----
        short8 a0 = lds_afrag(catw, t, 0, q);
        short8 a1 = lds_afrag(catw, t, 1, q);
        float hv[4][4];
#pragma unroll
        for (int nt = 0; nt < 4; ++nt) {
            f32x4 a = zf;
            a = MFMA(a0, wnb[0][nt], a);
            a = MFMA(a1, wnb[1][nt], a);
            float2 pr = s_pr_nb[nt * 16 + t];
#pragma unroll
            for (int r = 0; r < 4; ++r) {
                hv[nt][r] = lrelu(fmaf(a[r], pr.x, pr.y));
                hw[(q * 4 + r) * 68 + nt * 16 + t] = cvt1(hv[nt][r]);
            }
        }

        // ---- phase C: scores = h @ w_attn; softmax over m (no max-sub: |s|<<88); pool ----
        short8 h0 = lds_afrag(hw, t, 0, q);
        short8 h1 = lds_afrag(hw, t, 1, q);
        float pooled[4];
#pragma unroll
        for (int nt = 0; nt < 4; ++nt) {
            f32x4 s = zf;
            s = MFMA(h0, watt[0][nt], s);
            s = MFMA(h1, watt[1][nt], s);
            float num = 0.f, den = 0.f;
#pragma unroll
            for (int r = 0; r < 4; ++r) {
                float e = __expf(s[r]);
                num += e * hv[nt][r];
                den += e;
            }
            num += __shfl_xor(num, 16); den += __shfl_xor(den, 16);
            num += __shfl_xor(num, 32); den += __shfl_xor(den, 32);
            pooled[nt] = num / den;
        }
        float pv = (q == 0) ? pooled[0] : (q == 1) ? pooled[1]
                 : (q == 2) ? pooled[2] : pooled[3];
        poolw[p * 68 + q * 16 + t] = cvt1(pv);

        // rotate pipeline buffers (SSA vector copies)
        ga0 = gb0; ga1 = gb1; ra0 = rb0; ra1 = rb1; ixB = ixC;
    }

    // ---- epilogue: out = bn(pooled @ w_out); sc = bn(feat @ w_sc); lrelu(sum) ----
    short8 wout[2][4], wsc[4];
#pragma unroll
    for (int ks = 0; ks < 2; ++ks)
#pragma unroll
        for (int nt = 0; nt < 4; ++nt) wout[ks][nt] = load_bfrag(w_out, 64, 64, ks, nt, q, t);
#pragma unroll
    for (int nt = 0; nt < 4; ++nt) wsc[nt] = load_bfrag(w_sc, 32, 64, 0, nt, q, t);

    short8 pf0 = lds_afrag(poolw, t, 0, q);
    short8 pf1 = lds_afrag(poolw, t, 1, q);
    U8 sxu;
    {
        const float* fp = fpb + (size_t)(P0 + t) * 32 + q * 8;
        f32x4a v0 = *(const f32x4a*)fp;
        f32x4a v1 = *(const f32x4a*)(fp + 4);
        sxu.w[0] = cvt2(v0.x, v0.y); sxu.w[1] = cvt2(v0.z, v0.w);
        sxu.w[2] = cvt2(v1.x, v1.y); sxu.w[3] = cvt2(v1.z, v1.w);
    }
    short8 scf = sxu.s;
#pragma unroll
    for (int nt = 0; nt < 4; ++nt) {
        f32x4 oa = zf;
        oa = MFMA(pf0, wout[0][nt], oa);
        oa = MFMA(pf1, wout[1][nt], oa);
        f32x4 sa = MFMA(scf, wsc[nt], zf);
        float2 po = s_pr_out[nt * 16 + t];
        float2 ps = s_pr_sc[nt * 16 + t];
#pragma unroll
        for (int r = 0; r < 4; ++r) {
            float o  = fmaf(oa[r], po.x, po.y);
            float s2 = fmaf(sa[r], ps.x, ps.y);
            outp[(size_t)(P0 + q * 4 + r) * 64 + nt * 16 + t] = lrelu(o + s2);
        }
    }
}

extern "C" void kernel_launch(void* const* d_in, const int* in_sizes, int n_in,
                              void* d_out, int out_size, void* d_ws, size_t ws_size,
                              hipStream_t stream) {
    hipLaunchKernelGGL(lfa_kernel, dim3(2048), dim3(256), 0, stream,
                       d_in[0], d_in[1], (const int*)d_in[2],
                       d_in[3], d_in[4], d_in[5], d_in[6], d_in[7], d_in[8],
                       d_in[9], d_in[10], d_in[11], d_in[12], d_in[13], d_in[14],
                       d_in[15],
                       d_in[16], d_in[17], d_in[18], d_in[19], d_in[20], d_in[21],
                       d_in[22], d_in[23], d_in[24], d_in[25], d_in[26], d_in[27],
                       (float*)d_out);
}